// Round 4
// baseline (604.639 us; speedup 1.0000x reference)
//
#include <hip/hip_runtime.h>
#include <cstdint>
#include <cstddef>

// ---------------------------------------------------------------------------
// Problem constants (FeaturePropagationModule)
// ---------------------------------------------------------------------------
#define BATCHES   16
#define NC_PER    1024
#define NF_PER    4096
#define NC_TOT    (BATCHES * NC_PER)     // 16384
#define NF_TOT    (BATCHES * NF_PER)     // 65536
#define C_IN      512
#define C_SKIP    256
#define D_IN      (C_IN + C_SKIP)        // 768
#define C_OUT     512
#define BN_EPS    1e-5f

typedef __bf16 bf16x8 __attribute__((ext_vector_type(8)));
typedef __bf16 bf16x4 __attribute__((ext_vector_type(4)));
typedef float  f32x4  __attribute__((ext_vector_type(4)));

static_assert(sizeof(__bf16) == 2, "bf16 size");

// ---------------------------------------------------------------------------
// Kernel 1: transpose fp32 weight [K,N] -> bf16 [N,K]
// ---------------------------------------------------------------------------
__global__ __launch_bounds__(256) void transpose_to_bf16(
    const float* __restrict__ W, __bf16* __restrict__ Wt, int K, int N) {
  int idx = blockIdx.x * 256 + threadIdx.x;
  if (idx >= K * N) return;
  int n = idx / K;
  int k = idx - n * K;
  Wt[idx] = (__bf16)W[k * N + n];
}

// ---------------------------------------------------------------------------
// Kernel 2a: per-batch 3-NN (segmented scan, 4 segments of 256 per point).
// Distances replicate the numpy-fp32 oracle BIT-EXACTLY (per-op __f*_rn,
// numpy association order); lexicographic merge == stable ascending scan.
// ---------------------------------------------------------------------------
__global__ __launch_bounds__(256) void knn_kernel(
    const float* __restrict__ pos,      // [NC_TOT, 3]
    const float* __restrict__ pos_skip, // [NF_TOT, 3]
    int4*  __restrict__ idx3,           // [NF_TOT]
    float4* __restrict__ w3)            // [NF_TOT]
{
  __shared__ float s_pos[NC_PER * 3];   // 12 KiB
  __shared__ float s_pc2[NC_PER];       // 4 KiB
  __shared__ float s_pd[4][64][3];      // 3 KiB
  __shared__ int   s_pi[4][64][3];      // 3 KiB

  const int tid   = threadIdx.x;
  const int bi    = blockIdx.x;         // 1024 blocks
  const int fbase = bi * 64;
  const int b     = fbase >> 12;        // / NF_PER
  const int cbase = b * NC_PER;

  for (int i = tid; i < NC_PER * 3; i += 256)
    s_pos[i] = pos[(size_t)cbase * 3 + i];
  __syncthreads();
  for (int j = tid; j < NC_PER; j += 256) {
    float cx = s_pos[j * 3 + 0], cy = s_pos[j * 3 + 1], cz = s_pos[j * 3 + 2];
    s_pc2[j] = __fadd_rn(__fadd_rn(__fmul_rn(cx, cx), __fmul_rn(cy, cy)),
                         __fmul_rn(cz, cz));
  }
  __syncthreads();

  const int p   = tid & 63;
  const int seg = tid >> 6;
  const int f   = fbase + p;
  const float px = pos_skip[f * 3 + 0];
  const float py = pos_skip[f * 3 + 1];
  const float pz = pos_skip[f * 3 + 2];
  const float pf2 = __fadd_rn(__fadd_rn(__fmul_rn(px, px), __fmul_rn(py, py)),
                              __fmul_rn(pz, pz));
  float b0 = 1e30f, b1 = 1e30f, b2 = 1e30f;
  int   i0 = 0,     i1 = 0,     i2 = 0;
  const int j0 = seg * 256;
#pragma unroll 4
  for (int jj = 0; jj < 256; ++jj) {
    const int j = j0 + jj;
    float cx = s_pos[j * 3 + 0], cy = s_pos[j * 3 + 1], cz = s_pos[j * 3 + 2];
    float dot = __fadd_rn(__fadd_rn(__fmul_rn(px, cx), __fmul_rn(py, cy)),
                          __fmul_rn(pz, cz));
    float d2 = __fsub_rn(__fadd_rn(pf2, s_pc2[j]), __fmul_rn(2.0f, dot));
    if (d2 < b2) {                       // strict < keeps earliest (lowest j)
      if (d2 < b1) {
        b2 = b1; i2 = i1;
        if (d2 < b0) { b1 = b0; i1 = i0; b0 = d2; i0 = j; }
        else         { b1 = d2; i1 = j; }
      } else { b2 = d2; i2 = j; }
    }
  }
  s_pd[seg][p][0] = b0; s_pd[seg][p][1] = b1; s_pd[seg][p][2] = b2;
  s_pi[seg][p][0] = i0; s_pi[seg][p][1] = i1; s_pi[seg][p][2] = i2;
  __syncthreads();

  if (tid < 64) {
    float m0 = 1e30f, m1 = 1e30f, m2 = 1e30f;
    int  mi0 = 0,    mi1 = 0,    mi2 = 0;
#pragma unroll
    for (int s = 0; s < 4; ++s)
#pragma unroll
      for (int k = 0; k < 3; ++k) {
        float d = s_pd[s][tid][k];
        int   i = s_pi[s][tid][k];
        if (d < m2 || (d == m2 && i < mi2)) {
          if (d < m1 || (d == m1 && i < mi1)) {
            m2 = m1; mi2 = mi1;
            if (d < m0 || (d == m0 && i < mi0)) {
              m1 = m0; mi1 = mi0; m0 = d; mi0 = i;
            } else { m1 = d; mi1 = i; }
          } else { m2 = d; mi2 = i; }
        }
      }
    float w0 = 1.0f / fmaxf(m0, 1e-16f);
    float w1 = 1.0f / fmaxf(m1, 1e-16f);
    float w2 = 1.0f / fmaxf(m2, 1e-16f);
    float inv = 1.0f / __fadd_rn(__fadd_rn(w0, w1), w2);
    const int fo = fbase + tid;
    idx3[fo] = make_int4(mi0, mi1, mi2, 0);
    w3[fo]   = make_float4(w0 * inv, w1 * inv, w2 * inv, 0.f);
  }
}

// ---------------------------------------------------------------------------
// Kernel 2b: gather + weighted sum + concat skip -> h0 bf16.
// One wave per fine point; XCD swizzle keeps each XCD's 2 x-slabs in its L2.
// ---------------------------------------------------------------------------
__global__ __launch_bounds__(256) void gather_interp(
    const float* __restrict__ x,        // [NC_TOT, C_IN]
    const float* __restrict__ x_skip,   // [NF_TOT, C_SKIP]
    const int4*  __restrict__ idx3,     // [NF_TOT]
    const float4* __restrict__ w3,      // [NF_TOT]
    __bf16* __restrict__ h0)            // [NF_TOT, D_IN]
{
  const int bi   = blockIdx.x;          // 16384 blocks
  const int xcd  = bi & 7;
  const int slot = bi >> 3;             // 0..2047
  const int batch = xcd * 2 + (slot >> 10);
  const int blk   = slot & 1023;
  const int wv = threadIdx.x >> 6, ln = threadIdx.x & 63;
  const int f = batch * NF_PER + blk * 4 + wv;
  const int cbase = batch * NC_PER;

  const int4   id = idx3[f];
  const float4 w  = w3[f];
  const float* x0 = x + (size_t)(cbase + id.x) * C_IN;
  const float* x1 = x + (size_t)(cbase + id.y) * C_IN;
  const float* x2 = x + (size_t)(cbase + id.z) * C_IN;
  __bf16* o = h0 + (size_t)f * D_IN;
  const int c0 = ln * 4;
#pragma unroll
  for (int it = 0; it < 2; ++it) {
    const int c = c0 + it * 256;
    float4 a0 = *(const float4*)(x0 + c);
    float4 a1 = *(const float4*)(x1 + c);
    float4 a2 = *(const float4*)(x2 + c);
    bf16x4 ov;
    ov[0] = (__bf16)(w.x * a0.x + w.y * a1.x + w.z * a2.x);
    ov[1] = (__bf16)(w.x * a0.y + w.y * a1.y + w.z * a2.y);
    ov[2] = (__bf16)(w.x * a0.z + w.y * a1.z + w.z * a2.z);
    ov[3] = (__bf16)(w.x * a0.w + w.y * a1.w + w.z * a2.w);
    *(bf16x4*)(o + c) = ov;
  }
  float4 s = *(const float4*)(x_skip + (size_t)f * C_SKIP + c0);
  bf16x4 sv;
  sv[0] = (__bf16)s.x; sv[1] = (__bf16)s.y;
  sv[2] = (__bf16)s.z; sv[3] = (__bf16)s.w;
  *(bf16x4*)(o + C_IN + c0) = sv;
}

// ---------------------------------------------------------------------------
// Kernel 3: bf16 MFMA GEMM + bias, with FUSED column stats (sum/sumsq of the
// post-bias pre-activation output -> BatchNorm operand) via quad shuffle
// reduce + atomicAdd. Grid is m-major (x=m,y=n): consecutive blocks share
// the B-tile in L2 and n-phase re-reads of A hit the 256 MiB L3.
// 128x128 tile, 4 waves (2x2 of 64x64), 16x16x32 bf16 MFMA, BK=32,
// global_load_lds width-16 staging (m97 recipe).
// ---------------------------------------------------------------------------
template <int K, bool BF16OUT>
__global__ __launch_bounds__(256) void gemm_bt(
    const __bf16* __restrict__ A,    // [M, K]
    const __bf16* __restrict__ Bt,   // [512, K]
    const float*  __restrict__ bias, // [512]
    void* __restrict__ Cout,         // [M, 512] (bf16 or f32)
    float* __restrict__ sums)        // [1024]: [0,512)=sum [512,1024)=sumsq
{
  __shared__ __align__(16) __bf16 As[128 * 32];
  __shared__ __align__(16) __bf16 Bs[128 * 32];

  const int tid  = threadIdx.x;
  const int wave = tid >> 6, lane = tid & 63;
  const int quad = lane >> 4, l16 = lane & 15;
  const int wm = wave >> 1, wn = wave & 1;
  const int m0 = blockIdx.x * 128, n0 = blockIdx.y * 128;

  f32x4 acc[4][4] = {};

  for (int k0 = 0; k0 < K; k0 += 32) {
    __syncthreads();
#pragma unroll
    for (int q = 0; q < 2; ++q) {
      const int chunk = q * 256 + wave * 64 + lane;  // 16B chunk id
      const int row = chunk >> 2;
      const int col = (chunk & 3) << 3;
      __builtin_amdgcn_global_load_lds(
          (const __attribute__((address_space(1))) unsigned int*)(A + (size_t)(m0 + row) * K + (k0 + col)),
          (__attribute__((address_space(3))) unsigned int*)(As + (q * 256 + wave * 64) * 8),
          16, 0, 0);
      __builtin_amdgcn_global_load_lds(
          (const __attribute__((address_space(1))) unsigned int*)(Bt + (size_t)(n0 + row) * K + (k0 + col)),
          (__attribute__((address_space(3))) unsigned int*)(Bs + (q * 256 + wave * 64) * 8),
          16, 0, 0);
    }
    __syncthreads();

    bf16x8 af[4], bfv[4];
#pragma unroll
    for (int t = 0; t < 4; ++t) {
      af[t]  = *(const bf16x8*)&As[(wm * 64 + t * 16 + l16) * 32 + quad * 8];
      bfv[t] = *(const bf16x8*)&Bs[(wn * 64 + t * 16 + l16) * 32 + quad * 8];
    }
#pragma unroll
    for (int tm = 0; tm < 4; ++tm)
#pragma unroll
      for (int tn = 0; tn < 4; ++tn)
        acc[tm][tn] = __builtin_amdgcn_mfma_f32_16x16x32_bf16(
            af[tm], bfv[tn], acc[tm][tn], 0, 0, 0);
  }

  // epilogue: C/D layout (verified m89/m91): n = lane&15, m = quad*4 + r
#pragma unroll
  for (int tn = 0; tn < 4; ++tn) {
    const int n = n0 + wn * 64 + tn * 16 + l16;
    const float bv = bias[n];
    float s = 0.f, ss = 0.f;
#pragma unroll
    for (int tm = 0; tm < 4; ++tm) {
      const int mb = m0 + wm * 64 + tm * 16 + quad * 4;
#pragma unroll
      for (int r = 0; r < 4; ++r) {
        const float v = acc[tm][tn][r] + bv;
        s += v; ss += v * v;
        if constexpr (BF16OUT)
          ((__bf16*)Cout)[(size_t)(mb + r) * 512 + n] = (__bf16)v;
        else
          ((float*)Cout)[(size_t)(mb + r) * 512 + n] = v;
      }
    }
    // reduce the 4 quads (lanes l16, l16+16, l16+32, l16+48 share column n)
    s  += __shfl_down(s, 32);  s  += __shfl_down(s, 16);
    ss += __shfl_down(ss, 32); ss += __shfl_down(ss, 16);
    if (quad == 0) {
      atomicAdd(&sums[n], s);
      atomicAdd(&sums[512 + n], ss);
    }
  }
}

// ab layout: [0,512) = scale a, [512,1024) = shift b:  y = a*h + b
__global__ void finalize_stats(const float* __restrict__ sums,
                               const float* __restrict__ g,
                               const float* __restrict__ be,
                               float* __restrict__ ab, float invM) {
  const int c = blockIdx.x * 256 + threadIdx.x;
  if (c < 512) {
    float mean = sums[c] * invM;
    float var  = sums[512 + c] * invM - mean * mean;
    float a = g[c] * rsqrtf(var + BN_EPS);
    ab[c] = a;
    ab[512 + c] = be[c] - mean * a;
  }
}

// ---------------------------------------------------------------------------
// In-place BN+ReLU on bf16 h1
// ---------------------------------------------------------------------------
__global__ __launch_bounds__(256) void bnrelu_bf16(
    __bf16* __restrict__ H, const float* __restrict__ ab) {
  const size_t e = ((size_t)blockIdx.x * 256 + threadIdx.x) * 4;
  const int c = (int)(e & 511);
  bf16x4* p = (bf16x4*)(H + e);
  bf16x4 h = *p;
#pragma unroll
  for (int i = 0; i < 4; ++i) {
    float v = (float)h[i];
    v = fmaxf(fmaf(v, ab[c + i], ab[512 + c + i]), 0.f);
    h[i] = (__bf16)v;
  }
  *p = h;
}

// ---------------------------------------------------------------------------
// BN+ReLU: read bf16 h2, write f32 out
// ---------------------------------------------------------------------------
__global__ __launch_bounds__(256) void bnrelu_b2f(
    const __bf16* __restrict__ H, const float* __restrict__ ab,
    float* __restrict__ O) {
  const size_t e = ((size_t)blockIdx.x * 256 + threadIdx.x) * 4;
  const int c = (int)(e & 511);
  bf16x4 h = *(const bf16x4*)(H + e);
  float4 o;
  o.x = fmaxf(fmaf((float)h[0], ab[c + 0], ab[512 + c + 0]), 0.f);
  o.y = fmaxf(fmaf((float)h[1], ab[c + 1], ab[512 + c + 1]), 0.f);
  o.z = fmaxf(fmaf((float)h[2], ab[c + 2], ab[512 + c + 2]), 0.f);
  o.w = fmaxf(fmaf((float)h[3], ab[c + 3], ab[512 + c + 3]), 0.f);
  *(float4*)(O + e) = o;
}

// ---------------------------------------------------------------------------
// Tail: pos_skip copy + batch ids as float
// ---------------------------------------------------------------------------
__global__ __launch_bounds__(256) void tail_kernel(
    const float* __restrict__ pos_skip, float* __restrict__ out2) {
  const int i = blockIdx.x * 256 + threadIdx.x;   // 0 .. 262143
  if (i < NF_TOT * 3) {
    out2[i] = pos_skip[i];
  } else {
    const int f = i - NF_TOT * 3;
    out2[i] = (float)(f >> 12);                   // f / NF_PER
  }
}

// ---------------------------------------------------------------------------
// Launch
// ---------------------------------------------------------------------------
extern "C" void kernel_launch(void* const* d_in, const int* in_sizes, int n_in,
                              void* d_out, int out_size, void* d_ws, size_t ws_size,
                              hipStream_t stream) {
  (void)in_sizes; (void)n_in; (void)out_size; (void)ws_size;

  const float* x        = (const float*)d_in[0];
  const float* pos      = (const float*)d_in[1];
  const float* x_skip   = (const float*)d_in[3];
  const float* pos_skip = (const float*)d_in[4];
  const float* W1  = (const float*)d_in[6];
  const float* b1  = (const float*)d_in[7];
  const float* g1  = (const float*)d_in[8];
  const float* be1 = (const float*)d_in[9];
  const float* W2  = (const float*)d_in[10];
  const float* b2  = (const float*)d_in[11];
  const float* g2  = (const float*)d_in[12];
  const float* be2 = (const float*)d_in[13];
  float* out = (float*)d_out;

  char* ws = (char*)d_ws;
  // workspace layout (bytes). h2 aliases h0 (h0 dead after gemm1).
  __bf16* h0   = (__bf16*)(ws);                          // 100,663,296  h0 [65536,768]
  __bf16* h2   = (__bf16*)(ws);                          //  67,108,864  h2 [65536,512]
  __bf16* h1   = (__bf16*)(ws + 100663296ull);           //  67,108,864  h1 [65536,512]
  __bf16* W1t  = (__bf16*)(ws + 167772160ull);           //     786,432  [512,768]
  __bf16* W2t  = (__bf16*)(ws + 168558592ull);           //     524,288  [512,512]
  float*  sums1 = (float*)(ws + 169082880ull);           //       4,096
  float*  ab1   = (float*)(ws + 169086976ull);           //       4,096
  float*  sums2 = (float*)(ws + 169091072ull);           //       4,096
  float*  ab2   = (float*)(ws + 169095168ull);           //       4,096
  int4*   idx3  = (int4*)(ws + 169099264ull);            //   1,048,576  [65536]
  float4* w3    = (float4*)(ws + 170147840ull);          //   1,048,576  [65536]

  hipMemsetAsync(sums1, 0, 4096, stream);
  hipMemsetAsync(sums2, 0, 4096, stream);

  // weights -> transposed bf16
  transpose_to_bf16<<<(D_IN * C_OUT + 255) / 256, 256, 0, stream>>>(W1, W1t, D_IN, C_OUT);
  transpose_to_bf16<<<(C_OUT * C_OUT + 255) / 256, 256, 0, stream>>>(W2, W2t, C_OUT, C_OUT);

  // knn (segmented) then gather+concat -> h0
  knn_kernel<<<NF_TOT / 64, 256, 0, stream>>>(pos, pos_skip, idx3, w3);
  gather_interp<<<NF_TOT / 4, 256, 0, stream>>>(x, x_skip, idx3, w3, h0);

  // layer 1: gemm (+fused stats) -> bn scale/shift -> in-place bn+relu
  gemm_bt<D_IN, true><<<dim3(512, 4), 256, 0, stream>>>(h0, W1t, b1, (void*)h1, sums1);
  finalize_stats<<<2, 256, 0, stream>>>(sums1, g1, be1, ab1, 1.0f / (float)NF_TOT);
  bnrelu_bf16<<<(NF_TOT * 512 / 4) / 256, 256, 0, stream>>>(h1, ab1);

  // layer 2: gemm -> bf16 h2 (+fused stats) -> bn+relu -> f32 out
  gemm_bt<C_OUT, true><<<dim3(512, 4), 256, 0, stream>>>(h1, W2t, b2, (void*)h2, sums2);
  finalize_stats<<<2, 256, 0, stream>>>(sums2, g2, be2, ab2, 1.0f / (float)NF_TOT);
  bnrelu_b2f<<<(NF_TOT * 512 / 4) / 256, 256, 0, stream>>>(h2, ab2, out);

  // pos_skip + batch_skip outputs
  tail_kernel<<<(NF_TOT * 3 + NF_TOT + 255) / 256, 256, 0, stream>>>(
      pos_skip, out + (size_t)NF_TOT * 512);
}

// Round 5
// 530.156 us; speedup vs baseline: 1.1405x; 1.1405x over previous
//
#include <hip/hip_runtime.h>
#include <cstdint>
#include <cstddef>

// ---------------------------------------------------------------------------
// Problem constants (FeaturePropagationModule)
// ---------------------------------------------------------------------------
#define BATCHES   16
#define NC_PER    1024
#define NF_PER    4096
#define NC_TOT    (BATCHES * NC_PER)     // 16384
#define NF_TOT    (BATCHES * NF_PER)     // 65536
#define C_IN      512
#define C_SKIP    256
#define D_IN      (C_IN + C_SKIP)        // 768
#define C_OUT     512
#define BN_EPS    1e-5f

typedef __bf16 bf16x8 __attribute__((ext_vector_type(8)));
typedef __bf16 bf16x4 __attribute__((ext_vector_type(4)));
typedef float  f32x4  __attribute__((ext_vector_type(4)));

static_assert(sizeof(__bf16) == 2, "bf16 size");

// ---------------------------------------------------------------------------
// Kernel 1: transpose fp32 weight [K,N] -> bf16 [N,K]
// ---------------------------------------------------------------------------
__global__ __launch_bounds__(256) void transpose_to_bf16(
    const float* __restrict__ W, __bf16* __restrict__ Wt, int K, int N) {
  int idx = blockIdx.x * 256 + threadIdx.x;
  if (idx >= K * N) return;
  int n = idx / K;
  int k = idx - n * K;
  Wt[idx] = (__bf16)W[k * N + n];
}

// ---------------------------------------------------------------------------
// Kernel 2a: per-batch 3-NN (segmented scan, 4 segments of 256 per point).
// Distances replicate the numpy-fp32 oracle BIT-EXACTLY (per-op __f*_rn,
// numpy association order); lexicographic merge == stable ascending scan.
// ---------------------------------------------------------------------------
__global__ __launch_bounds__(256) void knn_kernel(
    const float* __restrict__ pos,      // [NC_TOT, 3]
    const float* __restrict__ pos_skip, // [NF_TOT, 3]
    int4*  __restrict__ idx3,           // [NF_TOT]
    float4* __restrict__ w3)            // [NF_TOT]
{
  __shared__ float s_pos[NC_PER * 3];   // 12 KiB
  __shared__ float s_pc2[NC_PER];       // 4 KiB
  __shared__ float s_pd[4][64][3];      // 3 KiB
  __shared__ int   s_pi[4][64][3];      // 3 KiB

  const int tid   = threadIdx.x;
  const int bi    = blockIdx.x;         // 1024 blocks
  const int fbase = bi * 64;
  const int b     = fbase >> 12;        // / NF_PER
  const int cbase = b * NC_PER;

  for (int i = tid; i < NC_PER * 3; i += 256)
    s_pos[i] = pos[(size_t)cbase * 3 + i];
  __syncthreads();
  for (int j = tid; j < NC_PER; j += 256) {
    float cx = s_pos[j * 3 + 0], cy = s_pos[j * 3 + 1], cz = s_pos[j * 3 + 2];
    s_pc2[j] = __fadd_rn(__fadd_rn(__fmul_rn(cx, cx), __fmul_rn(cy, cy)),
                         __fmul_rn(cz, cz));
  }
  __syncthreads();

  const int p   = tid & 63;
  const int seg = tid >> 6;
  const int f   = fbase + p;
  const float px = pos_skip[f * 3 + 0];
  const float py = pos_skip[f * 3 + 1];
  const float pz = pos_skip[f * 3 + 2];
  const float pf2 = __fadd_rn(__fadd_rn(__fmul_rn(px, px), __fmul_rn(py, py)),
                              __fmul_rn(pz, pz));
  float b0 = 1e30f, b1 = 1e30f, b2 = 1e30f;
  int   i0 = 0,     i1 = 0,     i2 = 0;
  const int j0 = seg * 256;
#pragma unroll 4
  for (int jj = 0; jj < 256; ++jj) {
    const int j = j0 + jj;
    float cx = s_pos[j * 3 + 0], cy = s_pos[j * 3 + 1], cz = s_pos[j * 3 + 2];
    float dot = __fadd_rn(__fadd_rn(__fmul_rn(px, cx), __fmul_rn(py, cy)),
                          __fmul_rn(pz, cz));
    float d2 = __fsub_rn(__fadd_rn(pf2, s_pc2[j]), __fmul_rn(2.0f, dot));
    if (d2 < b2) {                       // strict < keeps earliest (lowest j)
      if (d2 < b1) {
        b2 = b1; i2 = i1;
        if (d2 < b0) { b1 = b0; i1 = i0; b0 = d2; i0 = j; }
        else         { b1 = d2; i1 = j; }
      } else { b2 = d2; i2 = j; }
    }
  }
  s_pd[seg][p][0] = b0; s_pd[seg][p][1] = b1; s_pd[seg][p][2] = b2;
  s_pi[seg][p][0] = i0; s_pi[seg][p][1] = i1; s_pi[seg][p][2] = i2;
  __syncthreads();

  if (tid < 64) {
    float m0 = 1e30f, m1 = 1e30f, m2 = 1e30f;
    int  mi0 = 0,    mi1 = 0,    mi2 = 0;
#pragma unroll
    for (int s = 0; s < 4; ++s)
#pragma unroll
      for (int k = 0; k < 3; ++k) {
        float d = s_pd[s][tid][k];
        int   i = s_pi[s][tid][k];
        if (d < m2 || (d == m2 && i < mi2)) {
          if (d < m1 || (d == m1 && i < mi1)) {
            m2 = m1; mi2 = mi1;
            if (d < m0 || (d == m0 && i < mi0)) {
              m1 = m0; mi1 = mi0; m0 = d; mi0 = i;
            } else { m1 = d; mi1 = i; }
          } else { m2 = d; mi2 = i; }
        }
      }
    float w0 = 1.0f / fmaxf(m0, 1e-16f);
    float w1 = 1.0f / fmaxf(m1, 1e-16f);
    float w2 = 1.0f / fmaxf(m2, 1e-16f);
    float inv = 1.0f / __fadd_rn(__fadd_rn(w0, w1), w2);
    const int fo = fbase + tid;
    idx3[fo] = make_int4(mi0, mi1, mi2, 0);
    w3[fo]   = make_float4(w0 * inv, w1 * inv, w2 * inv, 0.f);
  }
}

// ---------------------------------------------------------------------------
// Kernel 2b: gather + weighted sum + concat skip -> h0 bf16.
// One wave per fine point; XCD swizzle keeps each XCD's 2 x-slabs in its L2.
// ---------------------------------------------------------------------------
__global__ __launch_bounds__(256) void gather_interp(
    const float* __restrict__ x,        // [NC_TOT, C_IN]
    const float* __restrict__ x_skip,   // [NF_TOT, C_SKIP]
    const int4*  __restrict__ idx3,     // [NF_TOT]
    const float4* __restrict__ w3,      // [NF_TOT]
    __bf16* __restrict__ h0)            // [NF_TOT, D_IN]
{
  const int bi   = blockIdx.x;          // 16384 blocks
  const int xcd  = bi & 7;
  const int slot = bi >> 3;             // 0..2047
  const int batch = xcd * 2 + (slot >> 10);
  const int blk   = slot & 1023;
  const int wv = threadIdx.x >> 6, ln = threadIdx.x & 63;
  const int f = batch * NF_PER + blk * 4 + wv;
  const int cbase = batch * NC_PER;

  const int4   id = idx3[f];
  const float4 w  = w3[f];
  const float* x0 = x + (size_t)(cbase + id.x) * C_IN;
  const float* x1 = x + (size_t)(cbase + id.y) * C_IN;
  const float* x2 = x + (size_t)(cbase + id.z) * C_IN;
  __bf16* o = h0 + (size_t)f * D_IN;
  const int c0 = ln * 4;
#pragma unroll
  for (int it = 0; it < 2; ++it) {
    const int c = c0 + it * 256;
    float4 a0 = *(const float4*)(x0 + c);
    float4 a1 = *(const float4*)(x1 + c);
    float4 a2 = *(const float4*)(x2 + c);
    bf16x4 ov;
    ov[0] = (__bf16)(w.x * a0.x + w.y * a1.x + w.z * a2.x);
    ov[1] = (__bf16)(w.x * a0.y + w.y * a1.y + w.z * a2.y);
    ov[2] = (__bf16)(w.x * a0.z + w.y * a1.z + w.z * a2.z);
    ov[3] = (__bf16)(w.x * a0.w + w.y * a1.w + w.z * a2.w);
    *(bf16x4*)(o + c) = ov;
  }
  float4 s = *(const float4*)(x_skip + (size_t)f * C_SKIP + c0);
  bf16x4 sv;
  sv[0] = (__bf16)s.x; sv[1] = (__bf16)s.y;
  sv[2] = (__bf16)s.z; sv[3] = (__bf16)s.w;
  *(bf16x4*)(o + C_IN + c0) = sv;
}

// ---------------------------------------------------------------------------
// Kernel 3: bf16 MFMA GEMM + bias, with fused column stats written as
// NON-ATOMIC per-block partials (part1[mblk][1024]: [0,512)=sum,
// [512,1024)=sumsq; every slot written exactly once -> no zeroing, no
// contention). Grid n-major dim3(4,512) (the R3-measured 91 us config).
// 128x128 tile, 4 waves (2x2 of 64x64), 16x16x32 bf16 MFMA, BK=32,
// global_load_lds width-16 staging (m97 recipe).
// ---------------------------------------------------------------------------
template <int K, bool BF16OUT>
__global__ __launch_bounds__(256) void gemm_bt(
    const __bf16* __restrict__ A,    // [M, K]
    const __bf16* __restrict__ Bt,   // [512, K]
    const float*  __restrict__ bias, // [512]
    void* __restrict__ Cout,         // [M, 512] (bf16 or f32)
    float* __restrict__ part1)       // [512][1024] per-mblock partials
{
  __shared__ __align__(16) __bf16 As[128 * 32];
  __shared__ __align__(16) __bf16 Bs[128 * 32];
  __shared__ float s_red[2][4][16][2];   // [wn][tn][l16][sum/ss], 1 KiB

  const int tid  = threadIdx.x;
  const int wave = tid >> 6, lane = tid & 63;
  const int quad = lane >> 4, l16 = lane & 15;
  const int wm = wave >> 1, wn = wave & 1;
  const int m0 = blockIdx.y * 128, n0 = blockIdx.x * 128;

  f32x4 acc[4][4] = {};

  for (int k0 = 0; k0 < K; k0 += 32) {
    __syncthreads();
#pragma unroll
    for (int q = 0; q < 2; ++q) {
      const int chunk = q * 256 + wave * 64 + lane;  // 16B chunk id
      const int row = chunk >> 2;
      const int col = (chunk & 3) << 3;
      __builtin_amdgcn_global_load_lds(
          (const __attribute__((address_space(1))) unsigned int*)(A + (size_t)(m0 + row) * K + (k0 + col)),
          (__attribute__((address_space(3))) unsigned int*)(As + (q * 256 + wave * 64) * 8),
          16, 0, 0);
      __builtin_amdgcn_global_load_lds(
          (const __attribute__((address_space(1))) unsigned int*)(Bt + (size_t)(n0 + row) * K + (k0 + col)),
          (__attribute__((address_space(3))) unsigned int*)(Bs + (q * 256 + wave * 64) * 8),
          16, 0, 0);
    }
    __syncthreads();

    bf16x8 af[4], bfv[4];
#pragma unroll
    for (int t = 0; t < 4; ++t) {
      af[t]  = *(const bf16x8*)&As[(wm * 64 + t * 16 + l16) * 32 + quad * 8];
      bfv[t] = *(const bf16x8*)&Bs[(wn * 64 + t * 16 + l16) * 32 + quad * 8];
    }
#pragma unroll
    for (int tm = 0; tm < 4; ++tm)
#pragma unroll
      for (int tn = 0; tn < 4; ++tn)
        acc[tm][tn] = __builtin_amdgcn_mfma_f32_16x16x32_bf16(
            af[tm], bfv[tn], acc[tm][tn], 0, 0, 0);
  }

  // epilogue: C/D layout (verified m89/m91): n = lane&15, m = quad*4 + r
  float sArr[4], ssArr[4];
#pragma unroll
  for (int tn = 0; tn < 4; ++tn) {
    const int n = n0 + wn * 64 + tn * 16 + l16;
    const float bv = bias[n];
    float s = 0.f, ss = 0.f;
#pragma unroll
    for (int tm = 0; tm < 4; ++tm) {
      const int mb = m0 + wm * 64 + tm * 16 + quad * 4;
#pragma unroll
      for (int r = 0; r < 4; ++r) {
        const float v = acc[tm][tn][r] + bv;
        s += v; ss += v * v;
        if constexpr (BF16OUT)
          ((__bf16*)Cout)[(size_t)(mb + r) * 512 + n] = (__bf16)v;
        else
          ((float*)Cout)[(size_t)(mb + r) * 512 + n] = v;
      }
    }
    // reduce the 4 quads (lanes l16, l16+16, l16+32, l16+48 share column n)
    s  += __shfl_down(s, 32);  s  += __shfl_down(s, 16);
    ss += __shfl_down(ss, 32); ss += __shfl_down(ss, 16);
    sArr[tn] = s; ssArr[tn] = ss;
  }
  // combine the two m-waves (wm=0/1) via LDS, then one coalesced store
  if (wm == 1 && quad == 0) {
#pragma unroll
    for (int tn = 0; tn < 4; ++tn) {
      s_red[wn][tn][l16][0] = sArr[tn];
      s_red[wn][tn][l16][1] = ssArr[tn];
    }
  }
  __syncthreads();
  if (wm == 0 && quad == 0) {
    float* row = part1 + (size_t)blockIdx.y * 1024;
#pragma unroll
    for (int tn = 0; tn < 4; ++tn) {
      const int n = n0 + wn * 64 + tn * 16 + l16;
      row[n]       = sArr[tn]  + s_red[wn][tn][l16][0];
      row[512 + n] = ssArr[tn] + s_red[wn][tn][l16][1];
    }
  }
}

// ---------------------------------------------------------------------------
// Stage A: fold part1[512][1024] -> part2[16][1024] (coalesced)
// ---------------------------------------------------------------------------
__global__ __launch_bounds__(256) void reduce_partials(
    const float* __restrict__ part1, float* __restrict__ part2) {
  const int rb = blockIdx.x;            // 16 blocks, 32 rows each
  const int t  = threadIdx.x;
#pragma unroll
  for (int k = 0; k < 4; ++k) {
    const int c = k * 256 + t;
    float acc = 0.f;
    const float* p = part1 + (size_t)rb * 32 * 1024 + c;
#pragma unroll 8
    for (int r = 0; r < 32; ++r) { acc += *p; p += 1024; }
    part2[rb * 1024 + c] = acc;
  }
}

// ab layout: [0,512) = scale a, [512,1024) = shift b:  y = a*h + b
__global__ void finalize_stats(const float* __restrict__ part2,
                               const float* __restrict__ g,
                               const float* __restrict__ be,
                               float* __restrict__ ab, float invM) {
  const int c = blockIdx.x * 256 + threadIdx.x;
  if (c < 512) {
    float s = 0.f, ss = 0.f;
#pragma unroll
    for (int r = 0; r < 16; ++r) {
      s  += part2[r * 1024 + c];
      ss += part2[r * 1024 + 512 + c];
    }
    float mean = s * invM;
    float var  = ss * invM - mean * mean;
    float a = g[c] * rsqrtf(var + BN_EPS);
    ab[c] = a;
    ab[512 + c] = be[c] - mean * a;
  }
}

// ---------------------------------------------------------------------------
// In-place BN+ReLU on bf16 h1
// ---------------------------------------------------------------------------
__global__ __launch_bounds__(256) void bnrelu_bf16(
    __bf16* __restrict__ H, const float* __restrict__ ab) {
  const size_t e = ((size_t)blockIdx.x * 256 + threadIdx.x) * 4;
  const int c = (int)(e & 511);
  bf16x4* p = (bf16x4*)(H + e);
  bf16x4 h = *p;
#pragma unroll
  for (int i = 0; i < 4; ++i) {
    float v = (float)h[i];
    v = fmaxf(fmaf(v, ab[c + i], ab[512 + c + i]), 0.f);
    h[i] = (__bf16)v;
  }
  *p = h;
}

// ---------------------------------------------------------------------------
// BN+ReLU: read bf16 h2, write f32 out
// ---------------------------------------------------------------------------
__global__ __launch_bounds__(256) void bnrelu_b2f(
    const __bf16* __restrict__ H, const float* __restrict__ ab,
    float* __restrict__ O) {
  const size_t e = ((size_t)blockIdx.x * 256 + threadIdx.x) * 4;
  const int c = (int)(e & 511);
  bf16x4 h = *(const bf16x4*)(H + e);
  float4 o;
  o.x = fmaxf(fmaf((float)h[0], ab[c + 0], ab[512 + c + 0]), 0.f);
  o.y = fmaxf(fmaf((float)h[1], ab[c + 1], ab[512 + c + 1]), 0.f);
  o.z = fmaxf(fmaf((float)h[2], ab[c + 2], ab[512 + c + 2]), 0.f);
  o.w = fmaxf(fmaf((float)h[3], ab[c + 3], ab[512 + c + 3]), 0.f);
  *(float4*)(O + e) = o;
}

// ---------------------------------------------------------------------------
// Tail: pos_skip copy + batch ids as float
// ---------------------------------------------------------------------------
__global__ __launch_bounds__(256) void tail_kernel(
    const float* __restrict__ pos_skip, float* __restrict__ out2) {
  const int i = blockIdx.x * 256 + threadIdx.x;   // 0 .. 262143
  if (i < NF_TOT * 3) {
    out2[i] = pos_skip[i];
  } else {
    const int f = i - NF_TOT * 3;
    out2[i] = (float)(f >> 12);                   // f / NF_PER
  }
}

// ---------------------------------------------------------------------------
// Launch
// ---------------------------------------------------------------------------
extern "C" void kernel_launch(void* const* d_in, const int* in_sizes, int n_in,
                              void* d_out, int out_size, void* d_ws, size_t ws_size,
                              hipStream_t stream) {
  (void)in_sizes; (void)n_in; (void)out_size; (void)ws_size;

  const float* x        = (const float*)d_in[0];
  const float* pos      = (const float*)d_in[1];
  const float* x_skip   = (const float*)d_in[3];
  const float* pos_skip = (const float*)d_in[4];
  const float* W1  = (const float*)d_in[6];
  const float* b1  = (const float*)d_in[7];
  const float* g1  = (const float*)d_in[8];
  const float* be1 = (const float*)d_in[9];
  const float* W2  = (const float*)d_in[10];
  const float* b2  = (const float*)d_in[11];
  const float* g2  = (const float*)d_in[12];
  const float* be2 = (const float*)d_in[13];
  float* out = (float*)d_out;

  char* ws = (char*)d_ws;
  // workspace layout (bytes). h2 aliases h0 (h0 dead after gemm1).
  // part1 reuses the idx3/w3 region (dead after gather_interp).
  __bf16* h0   = (__bf16*)(ws);                          // 100,663,296  h0 [65536,768]
  __bf16* h2   = (__bf16*)(ws);                          //  67,108,864  h2 [65536,512]
  __bf16* h1   = (__bf16*)(ws + 100663296ull);           //  67,108,864  h1 [65536,512]
  __bf16* W1t  = (__bf16*)(ws + 167772160ull);           //     786,432  [512,768]
  __bf16* W2t  = (__bf16*)(ws + 168558592ull);           //     524,288  [512,512]
  float*  ab1   = (float*)(ws + 169086976ull);           //       4,096
  float*  ab2   = (float*)(ws + 169095168ull);           //       4,096
  int4*   idx3  = (int4*)(ws + 169099264ull);            //   1,048,576  [65536]
  float4* w3    = (float4*)(ws + 170147840ull);          //   1,048,576  [65536]
  float*  part1 = (float*)(ws + 169099264ull);           //   2,097,152  aliases idx3+w3
  float*  part2 = (float*)(ws + 171196416ull);           //      65,536  [16][1024]

  // weights -> transposed bf16
  transpose_to_bf16<<<(D_IN * C_OUT + 255) / 256, 256, 0, stream>>>(W1, W1t, D_IN, C_OUT);
  transpose_to_bf16<<<(C_OUT * C_OUT + 255) / 256, 256, 0, stream>>>(W2, W2t, C_OUT, C_OUT);

  // knn (segmented) then gather+concat -> h0
  knn_kernel<<<NF_TOT / 64, 256, 0, stream>>>(pos, pos_skip, idx3, w3);
  gather_interp<<<NF_TOT / 4, 256, 0, stream>>>(x, x_skip, idx3, w3, h0);

  // layer 1: gemm (+fused partial stats) -> reduce -> bn -> in-place bn+relu
  gemm_bt<D_IN, true><<<dim3(4, 512), 256, 0, stream>>>(h0, W1t, b1, (void*)h1, part1);
  reduce_partials<<<16, 256, 0, stream>>>(part1, part2);
  finalize_stats<<<2, 256, 0, stream>>>(part2, g1, be1, ab1, 1.0f / (float)NF_TOT);
  bnrelu_bf16<<<(NF_TOT * 512 / 4) / 256, 256, 0, stream>>>(h1, ab1);

  // layer 2: gemm -> bf16 h2 (+fused partial stats) -> bn+relu -> f32 out
  gemm_bt<C_OUT, true><<<dim3(4, 512), 256, 0, stream>>>(h1, W2t, b2, (void*)h2, part1);
  reduce_partials<<<16, 256, 0, stream>>>(part1, part2);
  finalize_stats<<<2, 256, 0, stream>>>(part2, g2, be2, ab2, 1.0f / (float)NF_TOT);
  bnrelu_b2f<<<(NF_TOT * 512 / 4) / 256, 256, 0, stream>>>(h2, ab2, out);

  // pos_skip + batch_skip outputs
  tail_kernel<<<(NF_TOT * 3 + NF_TOT + 255) / 256, 256, 0, stream>>>(
      pos_skip, out + (size_t)NF_TOT * 512);
}